// Round 1
// baseline (1383.343 us; speedup 1.0000x reference)
//
#include <hip/hip_runtime.h>

typedef _Float16 half8 __attribute__((ext_vector_type(8)));
typedef unsigned short ushort8 __attribute__((ext_vector_type(8)));
typedef float floatx4 __attribute__((ext_vector_type(4)));
typedef unsigned short u16;

#define NROWS 115200
#define MT 32

__device__ __forceinline__ void splitf(float f, u16& hi, u16& lo) {
    _Float16 h = (_Float16)f;
    _Float16 l = (_Float16)(f - (float)h);
    hi = __builtin_bit_cast(u16, h);
    lo = __builtin_bit_cast(u16, l);
}

// swizzled index into a [MT][256] fp16 LDS plane (16B-block XOR swizzle)
__device__ __forceinline__ int swz(int row, int col) {
    return row * 256 + ((((col >> 3)) ^ (row & 31)) << 3) + (col & 7);
}

// Pack src[K][N] fp32 into fragment-major split-fp16 planes:
// dst[((nt*kfrags + kf)*16 + m)*8 + j] = src[kf*8+j][nt*16+m]
__global__ void prep_pack(const float* __restrict__ src, u16* __restrict__ dhi,
                          u16* __restrict__ dlo, int K, int N, int Kd) {
    int kfrags = Kd >> 3;
    int nt = blockIdx.y;
    int frag = blockIdx.x * blockDim.x + threadIdx.x;
    if (frag >= kfrags * 16) return;
    int kf = frag >> 4, m = frag & 15;
    int n = nt * 16 + m;
    ushort8 vh, vl;
    #pragma unroll
    for (int j = 0; j < 8; ++j) {
        int k = kf * 8 + j;
        float v = (k < K && n < N) ? src[(size_t)k * N + n] : 0.f;
        u16 hi, lo; splitf(v, hi, lo);
        vh[j] = hi; vl[j] = lo;
    }
    size_t o = ((size_t)nt * kfrags + kf) * 128 + (size_t)m * 8;
    *(ushort8*)&dhi[o] = vh;
    *(ushort8*)&dlo[o] = vl;
}

// W23[k][n] = sum_j W2[k][j]*W3[j][n]   (256 x 157, fp32)
// b23[n]   = b3[n] + sum_j b2[j]*W3[j][n]
// block k (0..255), thread n: W3/W23 accesses coalesced, W2 row is scalar-uniform.
__global__ void w23_gemm(const float* __restrict__ W2, const float* __restrict__ W3,
                         const float* __restrict__ b2, const float* __restrict__ b3,
                         float* __restrict__ W23, float* __restrict__ b23) {
    int k = blockIdx.x, n = threadIdx.x;
    if (n >= 157) return;
    float acc = 0.f;
    for (int j = 0; j < 256; ++j)
        acc = fmaf(W2[k * 256 + j], W3[j * 157 + n], acc);
    W23[(size_t)k * 157 + n] = acc;
    if (k == 0) {
        float bb = b3[n];
        for (int j = 0; j < 256; ++j) bb = fmaf(b2[j], W3[j * 157 + n], bb);
        b23[n] = bb;
    }
}

__global__ __launch_bounds__(256, 2) void fused_head(
    const float* __restrict__ xg,
    const u16* __restrict__ w1h, const u16* __restrict__ w1l,
    const u16* __restrict__ w23h, const u16* __restrict__ w23l,
    const float* __restrict__ b1g, const float* __restrict__ b23g,
    const float* __restrict__ ipose, const float* __restrict__ ishape, const float* __restrict__ icam,
    float* __restrict__ out)
{
    // 70656 B static LDS (>64KB is fine on gfx950; 2 blocks/CU = 141KB <= 160KB)
    __shared__ __align__(16) u16 smem[35328];
    u16* xsh  = smem;              // x hi plane  [32][256] swz   (u16 0..8191)
    u16* hsh  = smem + 8192;       // h1 hi plane [32][256] swz
    u16* hsl  = smem + 16384;      // h1 lo plane
    u16* tsh  = smem + 24576;      // theta hi [32][168]
    u16* tsl  = smem + 29952;      // theta lo [32][168]
    u16* xslT = smem + 24576;      // TEMP x lo plane (overlays theta region, staging only)
    float* thf = (float*)smem;     // [32][144] fp32 pose (final; overlays xsh + head of hsh)

    const int t = threadIdx.x;
    const int lid = t & 63, wv = t >> 6;       // 4 waves
    const int q = lid >> 4, m = lid & 15;      // quad, lane-in-16
    const int fb = q * 128 + m * 8;            // fragment-local B offset
    const long rowbase = (long)blockIdx.x * MT;

    // ---- stage x tile: hi plane -> xsh, lo plane -> temp LDS ----
    #pragma unroll
    for (int i = 0; i < 4; ++i) {
        int idx = t + i * 256;
        int r = idx >> 5, s = idx & 31;
        const float4* sp = (const float4*)(xg + (rowbase + r) * 256 + s * 8);
        float4 f0 = sp[0], f1 = sp[1];
        float fv[8] = {f0.x, f0.y, f0.z, f0.w, f1.x, f1.y, f1.z, f1.w};
        ushort8 vh, vl;
        #pragma unroll
        for (int j = 0; j < 8; ++j) {
            u16 hi, lo; splitf(fv[j], hi, lo);
            vh[j] = hi; vl[j] = lo;
        }
        int o = r * 256 + ((s ^ (r & 31)) << 3);
        *(ushort8*)&xsh[o] = vh;
        *(ushort8*)&xslT[o] = vl;
    }
    __syncthreads();

    // ---- x lo fragments -> registers (identical for all waves; 64 VGPRs) ----
    half8 xl[2][8];
    #pragma unroll
    for (int rt = 0; rt < 2; ++rt)
        #pragma unroll
        for (int ks = 0; ks < 8; ++ks)
            xl[rt][ks] = *(const half8*)&xslT[swz(rt * 16 + m, ks * 32 + q * 8)];

    // ---- theta fp32 master in registers (GEMM23 C-frag layout) ----
    const int ncts = (wv < 2) ? 3 : 2;
    float tm[3][2][4];
    #pragma unroll
    for (int c = 0; c < 3; ++c) {
        int n3 = (wv + c * 4) * 16 + m;
        float v;
        if (n3 < 144)      v = ipose[n3];
        else if (n3 < 154) v = ishape[n3 - 144];
        else if (n3 < 157) v = icam[n3 - 154];
        else               v = 0.f;
        #pragma unroll
        for (int rt = 0; rt < 2; ++rt)
            #pragma unroll
            for (int r = 0; r < 4; ++r) tm[c][rt][r] = v;
    }
    __syncthreads();   // xslT fully consumed -> theta region reusable

    // ---- theta0 -> tsh/tsl ----
    #pragma unroll
    for (int c = 0; c < 3; ++c) {
        if (c < ncts) {
            int n3 = (wv + c * 4) * 16 + m;
            #pragma unroll
            for (int rt = 0; rt < 2; ++rt)
                #pragma unroll
                for (int r = 0; r < 4; ++r) {
                    int row = rt * 16 + q * 4 + r;
                    u16 hi, lo; splitf(tm[c][rt][r], hi, lo);
                    tsh[row * 168 + n3] = hi;
                    tsl[row * 168 + n3] = lo;
                }
        }
    }
    __syncthreads();

    const floatx4 zero4 = {0.f, 0.f, 0.f, 0.f};

    for (int it = 0; it < 3; ++it) {
        // ============ GEMM1: h1 = relu([x|theta] @ W1 + b1), K=416 ============
        floatx4 acc[4][2];
        #pragma unroll
        for (int ct = 0; ct < 4; ++ct)
            #pragma unroll
            for (int rt = 0; rt < 2; ++rt) acc[ct][rt] = zero4;

        // x part: A-hi from LDS, A-lo from registers (full unroll: xl compile-time indexed)
        #pragma unroll
        for (int ks = 0; ks < 8; ++ks) {
            half8 ah[2];
            #pragma unroll
            for (int rt = 0; rt < 2; ++rt)
                ah[rt] = *(const half8*)&xsh[swz(rt * 16 + m, ks * 32 + q * 8)];
            int bbase = wv * 26624 + ks * 512 + fb;
            #pragma unroll
            for (int ct = 0; ct < 4; ++ct) {
                half8 bh = *(const half8*)(w1h + bbase + ct * 6656);
                half8 bl = *(const half8*)(w1l + bbase + ct * 6656);
                #pragma unroll
                for (int rt = 0; rt < 2; ++rt) {
                    acc[ct][rt] = __builtin_amdgcn_mfma_f32_16x16x32_f16(ah[rt], bh, acc[ct][rt], 0, 0, 0);
                    acc[ct][rt] = __builtin_amdgcn_mfma_f32_16x16x32_f16(xl[rt][ks], bh, acc[ct][rt], 0, 0, 0);
                    acc[ct][rt] = __builtin_amdgcn_mfma_f32_16x16x32_f16(ah[rt], bl, acc[ct][rt], 0, 0, 0);
                }
            }
        }
        // theta part (K 256..415) from tsh/tsl
        #pragma unroll 1
        for (int ks = 8; ks < 13; ++ks) {
            int kp = (ks - 8) * 32 + q * 8;
            half8 ah[2], al[2];
            #pragma unroll
            for (int rt = 0; rt < 2; ++rt) {
                int o = (rt * 16 + m) * 168 + kp;
                ah[rt] = *(const half8*)&tsh[o];
                al[rt] = *(const half8*)&tsl[o];
            }
            int bbase = wv * 26624 + ks * 512 + fb;
            #pragma unroll
            for (int ct = 0; ct < 4; ++ct) {
                half8 bh = *(const half8*)(w1h + bbase + ct * 6656);
                half8 bl = *(const half8*)(w1l + bbase + ct * 6656);
                #pragma unroll
                for (int rt = 0; rt < 2; ++rt) {
                    acc[ct][rt] = __builtin_amdgcn_mfma_f32_16x16x32_f16(ah[rt], bh, acc[ct][rt], 0, 0, 0);
                    acc[ct][rt] = __builtin_amdgcn_mfma_f32_16x16x32_f16(al[rt], bh, acc[ct][rt], 0, 0, 0);
                    acc[ct][rt] = __builtin_amdgcn_mfma_f32_16x16x32_f16(ah[rt], bl, acc[ct][rt], 0, 0, 0);
                }
            }
        }
        // epi: bias + relu -> h planes. No pre-sync needed: h planes are disjoint
        // from tsh/xsh, and barrier collectiveness guarantees nobody is behind us
        // in a phase that reads h (previous readers all passed last iter's sync).
        #pragma unroll
        for (int ct = 0; ct < 4; ++ct) {
            int n = wv * 64 + ct * 16 + m;
            float bv = b1g[n];
            #pragma unroll
            for (int rt = 0; rt < 2; ++rt)
                #pragma unroll
                for (int r = 0; r < 4; ++r) {
                    int row = rt * 16 + q * 4 + r;
                    float v = fmaxf(acc[ct][rt][r] + bv, 0.f);
                    u16 hi, lo; splitf(v, hi, lo);
                    int o = swz(row, n);
                    hsh[o] = hi; hsl[o] = lo;
                }
        }
        __syncthreads();   // h1 visible

        // ======== GEMM23: theta += h1 @ (W2@W3) + b23, K=256, N=160(pad) ========
        floatx4 a3[3][2];
        #pragma unroll
        for (int c = 0; c < 3; ++c)
            #pragma unroll
            for (int rt = 0; rt < 2; ++rt) a3[c][rt] = zero4;

        #pragma unroll 2
        for (int ks = 0; ks < 8; ++ks) {
            half8 ah[2], al[2];
            #pragma unroll
            for (int rt = 0; rt < 2; ++rt) {
                int o = swz(rt * 16 + m, ks * 32 + q * 8);
                ah[rt] = *(const half8*)&hsh[o];
                al[rt] = *(const half8*)&hsl[o];
            }
            int bbase = ks * 512 + fb;
            #pragma unroll
            for (int c = 0; c < 3; ++c) {
                if (c < ncts) {
                    half8 bh = *(const half8*)(w23h + bbase + (wv + c * 4) * 4096);
                    half8 bl = *(const half8*)(w23l + bbase + (wv + c * 4) * 4096);
                    #pragma unroll
                    for (int rt = 0; rt < 2; ++rt) {
                        a3[c][rt] = __builtin_amdgcn_mfma_f32_16x16x32_f16(ah[rt], bh, a3[c][rt], 0, 0, 0);
                        a3[c][rt] = __builtin_amdgcn_mfma_f32_16x16x32_f16(al[rt], bh, a3[c][rt], 0, 0, 0);
                        a3[c][rt] = __builtin_amdgcn_mfma_f32_16x16x32_f16(ah[rt], bl, a3[c][rt], 0, 0, 0);
                    }
                }
            }
        }
        // fp32 residual update of theta master
        #pragma unroll
        for (int c = 0; c < 3; ++c) {
            if (c < ncts) {
                int n3 = (wv + c * 4) * 16 + m;
                float b3v = (n3 < 157) ? b23g[n3] : 0.f;
                #pragma unroll
                for (int rt = 0; rt < 2; ++rt)
                    #pragma unroll
                    for (int r = 0; r < 4; ++r)
                        tm[c][rt][r] += a3[c][rt][r] + b3v;
            }
        }

        if (it < 2) {
            // restage theta into its own region. Safe without a pre-sync: other
            // waves past sync1 only read h planes in GEMM23; theta readers (GEMM1
            // ks8..12) all completed before sync1 was collectively passed.
            #pragma unroll
            for (int c = 0; c < 3; ++c) {
                if (c < ncts) {
                    int n3 = (wv + c * 4) * 16 + m;
                    #pragma unroll
                    for (int rt = 0; rt < 2; ++rt)
                        #pragma unroll
                        for (int r = 0; r < 4; ++r) {
                            int row = rt * 16 + q * 4 + r;
                            u16 hi, lo; splitf(tm[c][rt][r], hi, lo);
                            tsh[row * 168 + n3] = hi;
                            tsl[row * 168 + n3] = lo;
                        }
                }
            }
            __syncthreads();   // theta' visible for next GEMM1
        } else {
            __syncthreads();   // all GEMM23 h-plane reads done (thf overlays xsh+hsh head)
            // final: pose -> fp32 LDS; betas/camera -> global fp32
            #pragma unroll
            for (int c = 0; c < 3; ++c) {
                if (c < ncts) {
                    int tile = wv + c * 4;
                    int n3 = tile * 16 + m;
                    if (tile < 9) {
                        #pragma unroll
                        for (int rt = 0; rt < 2; ++rt)
                            #pragma unroll
                            for (int r = 0; r < 4; ++r) {
                                int row = rt * 16 + q * 4 + r;
                                thf[row * 144 + n3] = tm[c][rt][r];
                            }
                    } else {  // tile 9: cols 144..159 = betas + camera
                        #pragma unroll
                        for (int rt = 0; rt < 2; ++rt)
                            #pragma unroll
                            for (int r = 0; r < 4; ++r) {
                                int row = rt * 16 + q * 4 + r;
                                long grow = rowbase + row;
                                float v = tm[c][rt][r];
                                if (m < 10)
                                    out[(size_t)NROWS * 216 + grow * 10 + m] = v;
                                else if (m < 13)
                                    out[(size_t)NROWS * 216 + (size_t)NROWS * 10 + grow * 3 + (m - 10)] = v;
                            }
                    }
                }
            }
            __syncthreads();
        }
    }

    // ============ epilogue: rot6d -> rotmat (fp32) ============
    {
        int r = t >> 3, g = t & 7;     // 8 threads per row, 3 joints each
        long grow = rowbase + r;
        #pragma unroll
        for (int jj = 0; jj < 3; ++jj) {
            int j = g * 3 + jj;
            const float* p = &thf[r * 144 + j * 6];
            float a1x = p[0], a2x = p[1], a1y = p[2], a2y = p[3], a1z = p[4], a2z = p[5];
            float n1 = fmaxf(sqrtf(a1x * a1x + a1y * a1y + a1z * a1z), 1e-12f);
            float b1x = a1x / n1, b1y = a1y / n1, b1z = a1z / n1;
            float d = b1x * a2x + b1y * a2y + b1z * a2z;
            float ux = a2x - d * b1x, uy = a2y - d * b1y, uz = a2z - d * b1z;
            float n2 = fmaxf(sqrtf(ux * ux + uy * uy + uz * uz), 1e-12f);
            float b2x = ux / n2, b2y = uy / n2, b2z = uz / n2;
            float b3x = b1y * b2z - b1z * b2y;
            float b3y = b1z * b2x - b1x * b2z;
            float b3z = b1x * b2y - b1y * b2x;
            float* o = out + (size_t)grow * 216 + j * 9;
            o[0] = b1x; o[1] = b2x; o[2] = b3x;
            o[3] = b1y; o[4] = b2y; o[5] = b3y;
            o[6] = b1z; o[7] = b2z; o[8] = b3z;
        }
    }
}

extern "C" void kernel_launch(void* const* d_in, const int* in_sizes, int n_in,
                              void* d_out, int out_size, void* d_ws, size_t ws_size,
                              hipStream_t stream) {
    const float* x  = (const float*)d_in[0];
    const float* W1 = (const float*)d_in[2];
    const float* b1 = (const float*)d_in[3];
    const float* W2 = (const float*)d_in[4];
    const float* b2 = (const float*)d_in[5];
    const float* W3 = (const float*)d_in[6];
    const float* b3 = (const float*)d_in[7];
    const float* ip = (const float*)d_in[8];
    const float* is = (const float*)d_in[9];
    const float* ic = (const float*)d_in[10];

    u16* w1h  = (u16*)d_ws;               // 16 nt * 52 kf * 128 = 106496
    u16* w1l  = w1h + 106496;
    u16* w23h = w1l + 106496;             // 10 nt * 32 kf * 128 = 40960
    u16* w23l = w23h + 40960;
    float* w23f = (float*)(w23l + 40960); // 256*157 fp32
    float* b23f = w23f + 256 * 157;       // 157 fp32

    w23_gemm<<<256, 192, 0, stream>>>(W2, W3, b2, b3, w23f, b23f);
    prep_pack<<<dim3(4, 16), 256, 0, stream>>>(W1, w1h, w1l, 413, 256, 416);
    prep_pack<<<dim3(2, 10), 256, 0, stream>>>(w23f, w23h, w23l, 256, 157, 256);

    fused_head<<<NROWS / MT, 256, 0, stream>>>(x, w1h, w1l, w23h, w23l,
                                               b1, b23f, ip, is, ic, (float*)d_out);
}

// Round 2
// 630.514 us; speedup vs baseline: 2.1940x; 2.1940x over previous
//
#include <hip/hip_runtime.h>

typedef _Float16 half8 __attribute__((ext_vector_type(8)));
typedef unsigned short ushort8 __attribute__((ext_vector_type(8)));
typedef float floatx4 __attribute__((ext_vector_type(4)));
typedef unsigned short u16;

#define NROWS 115200
#define MT 32

__device__ __forceinline__ void splitf(float f, u16& hi, u16& lo) {
    _Float16 h = (_Float16)f;
    _Float16 l = (_Float16)(f - (float)h);
    hi = __builtin_bit_cast(u16, h);
    lo = __builtin_bit_cast(u16, l);
}

// swizzled index into a [MT][256] fp16 LDS plane (16B-block XOR swizzle)
__device__ __forceinline__ int swz(int row, int col) {
    return row * 256 + ((((col >> 3)) ^ (row & 31)) << 3) + (col & 7);
}

// Pack src[K][N] fp32 into fragment-major split-fp16 planes:
// dst[((nt*kfrags + kf)*16 + m)*8 + j] = src[kf*8+j][nt*16+m]
__global__ void prep_pack(const float* __restrict__ src, u16* __restrict__ dhi,
                          u16* __restrict__ dlo, int K, int N, int Kd) {
    int kfrags = Kd >> 3;
    int nt = blockIdx.y;
    int frag = blockIdx.x * blockDim.x + threadIdx.x;
    if (frag >= kfrags * 16) return;
    int kf = frag >> 4, m = frag & 15;
    int n = nt * 16 + m;
    ushort8 vh, vl;
    #pragma unroll
    for (int j = 0; j < 8; ++j) {
        int k = kf * 8 + j;
        float v = (k < K && n < N) ? src[(size_t)k * N + n] : 0.f;
        u16 hi, lo; splitf(v, hi, lo);
        vh[j] = hi; vl[j] = lo;
    }
    size_t o = ((size_t)nt * kfrags + kf) * 128 + (size_t)m * 8;
    *(ushort8*)&dhi[o] = vh;
    *(ushort8*)&dlo[o] = vl;
}

// W23[k][n] = sum_j W2[k][j]*W3[j][n]   (256 x 157, fp32)
// b23[n]   = b3[n] + sum_j b2[j]*W3[j][n]
__global__ void w23_gemm(const float* __restrict__ W2, const float* __restrict__ W3,
                         const float* __restrict__ b2, const float* __restrict__ b3,
                         float* __restrict__ W23, float* __restrict__ b23) {
    int k = blockIdx.x, n = threadIdx.x;
    if (n >= 157) return;
    float acc = 0.f;
    for (int j = 0; j < 256; ++j)
        acc = fmaf(W2[k * 256 + j], W3[j * 157 + n], acc);
    W23[(size_t)k * 157 + n] = acc;
    if (k == 0) {
        float bb = b3[n];
        for (int j = 0; j < 256; ++j) bb = fmaf(b2[j], W3[j * 157 + n], bb);
        b23[n] = bb;
    }
}

__global__ __launch_bounds__(256, 2) void fused_head(
    const float* __restrict__ xg,
    const u16* __restrict__ w1h, const u16* __restrict__ w1l,
    const u16* __restrict__ w23h, const u16* __restrict__ w23l,
    const float* __restrict__ b1g, const float* __restrict__ b23g,
    const float* __restrict__ ipose, const float* __restrict__ ishape, const float* __restrict__ icam,
    float* __restrict__ out)
{
    __shared__ __align__(16) u16 smem[4 * MT * 256];
    u16* xsh = smem;                  // x hi plane
    u16* xsl = smem + MT * 256;       // x lo plane
    u16* hsh = smem + 2 * MT * 256;   // h / theta hi plane
    u16* hsl = smem + 3 * MT * 256;   // h / theta lo plane
    float* thf = (float*)smem;        // [MT][144] fp32 pose (epilogue only; overlays x planes)

    const int t = threadIdx.x;
    const int lid = t & 63, wv = t >> 6;       // 4 waves
    const int q = lid >> 4, m = lid & 15;      // quad, lane-in-16
    const int fb = q * 128 + m * 8;            // fragment-local B offset
    const long rowbase = (long)blockIdx.x * MT;

    // ---- stage x tile (32 rows x 256 fp32 -> split fp16 planes) ----
    #pragma unroll
    for (int i = 0; i < 4; ++i) {
        int idx = t + i * 256;
        int r = idx >> 5, s = idx & 31;
        const float4* sp = (const float4*)(xg + (rowbase + r) * 256 + s * 8);
        float4 f0 = sp[0], f1 = sp[1];
        float fv[8] = {f0.x, f0.y, f0.z, f0.w, f1.x, f1.y, f1.z, f1.w};
        ushort8 vh, vl;
        #pragma unroll
        for (int j = 0; j < 8; ++j) {
            u16 hi, lo; splitf(fv[j], hi, lo);
            vh[j] = hi; vl[j] = lo;
        }
        int o = r * 256 + ((s ^ (r & 31)) << 3);
        *(ushort8*)&xsh[o] = vh;
        *(ushort8*)&xsl[o] = vl;
    }

    // ---- theta fp32 master in registers (GEMM23 C-frag layout) ----
    const int ncts = (wv < 2) ? 3 : 2;
    float tm[3][2][4];
    #pragma unroll
    for (int c = 0; c < 3; ++c) {
        int n3 = (wv + c * 4) * 16 + m;
        float v;
        if (n3 < 144)      v = ipose[n3];
        else if (n3 < 154) v = ishape[n3 - 144];
        else if (n3 < 157) v = icam[n3 - 154];
        else               v = 0.f;
        #pragma unroll
        for (int rt = 0; rt < 2; ++rt)
            #pragma unroll
            for (int r = 0; r < 4; ++r) tm[c][rt][r] = v;
    }
    #pragma unroll
    for (int c = 0; c < 3; ++c) {
        if (c < ncts) {
            int n3 = (wv + c * 4) * 16 + m;
            #pragma unroll
            for (int rt = 0; rt < 2; ++rt)
                #pragma unroll
                for (int r = 0; r < 4; ++r) {
                    int row = rt * 16 + q * 4 + r;
                    u16 hi, lo; splitf(tm[c][rt][r], hi, lo);
                    hsh[row * 168 + n3] = hi;
                    hsl[row * 168 + n3] = lo;
                }
        }
    }
    __syncthreads();

    const floatx4 zero4 = {0.f, 0.f, 0.f, 0.f};

    for (int it = 0; it < 3; ++it) {
        // ============ GEMM1: h1 = relu([x|theta] @ W1 + b1), K=416 ============
        floatx4 acc[4][2];
        #pragma unroll
        for (int ct = 0; ct < 4; ++ct)
            #pragma unroll
            for (int rt = 0; rt < 2; ++rt) acc[ct][rt] = zero4;

        #pragma unroll 2
        for (int ks = 0; ks < 8; ++ks) {
            half8 ah[2], al[2];
            #pragma unroll
            for (int rt = 0; rt < 2; ++rt) {
                int o = swz(rt * 16 + m, ks * 32 + q * 8);
                ah[rt] = *(const half8*)&xsh[o];
                al[rt] = *(const half8*)&xsl[o];
            }
            int bbase = wv * 26624 + ks * 512 + fb;
            #pragma unroll
            for (int ct = 0; ct < 4; ++ct) {
                half8 bh = *(const half8*)(w1h + bbase + ct * 6656);
                half8 bl = *(const half8*)(w1l + bbase + ct * 6656);
                #pragma unroll
                for (int rt = 0; rt < 2; ++rt) {
                    acc[ct][rt] = __builtin_amdgcn_mfma_f32_16x16x32_f16(ah[rt], bh, acc[ct][rt], 0, 0, 0);
                    acc[ct][rt] = __builtin_amdgcn_mfma_f32_16x16x32_f16(al[rt], bh, acc[ct][rt], 0, 0, 0);
                    acc[ct][rt] = __builtin_amdgcn_mfma_f32_16x16x32_f16(ah[rt], bl, acc[ct][rt], 0, 0, 0);
                }
            }
        }
        #pragma unroll 1
        for (int ks = 8; ks < 13; ++ks) {
            int kp = (ks - 8) * 32 + q * 8;
            half8 ah[2], al[2];
            #pragma unroll
            for (int rt = 0; rt < 2; ++rt) {
                int o = (rt * 16 + m) * 168 + kp;
                ah[rt] = *(const half8*)&hsh[o];
                al[rt] = *(const half8*)&hsl[o];
            }
            int bbase = wv * 26624 + ks * 512 + fb;
            #pragma unroll
            for (int ct = 0; ct < 4; ++ct) {
                half8 bh = *(const half8*)(w1h + bbase + ct * 6656);
                half8 bl = *(const half8*)(w1l + bbase + ct * 6656);
                #pragma unroll
                for (int rt = 0; rt < 2; ++rt) {
                    acc[ct][rt] = __builtin_amdgcn_mfma_f32_16x16x32_f16(ah[rt], bh, acc[ct][rt], 0, 0, 0);
                    acc[ct][rt] = __builtin_amdgcn_mfma_f32_16x16x32_f16(al[rt], bh, acc[ct][rt], 0, 0, 0);
                    acc[ct][rt] = __builtin_amdgcn_mfma_f32_16x16x32_f16(ah[rt], bl, acc[ct][rt], 0, 0, 0);
                }
            }
        }
        __syncthreads();   // theta reads done -> h planes reusable
        #pragma unroll
        for (int ct = 0; ct < 4; ++ct) {
            int n = wv * 64 + ct * 16 + m;
            float bv = b1g[n];
            #pragma unroll
            for (int rt = 0; rt < 2; ++rt)
                #pragma unroll
                for (int r = 0; r < 4; ++r) {
                    int row = rt * 16 + q * 4 + r;
                    float v = fmaxf(acc[ct][rt][r] + bv, 0.f);
                    u16 hi, lo; splitf(v, hi, lo);
                    int o = swz(row, n);
                    hsh[o] = hi; hsl[o] = lo;
                }
        }
        __syncthreads();   // h1 visible

        // ======== GEMM23: theta += h1 @ (W2@W3) + b23, K=256, N=160(pad) ========
        floatx4 a3[3][2];
        #pragma unroll
        for (int c = 0; c < 3; ++c)
            #pragma unroll
            for (int rt = 0; rt < 2; ++rt) a3[c][rt] = zero4;

        #pragma unroll 2
        for (int ks = 0; ks < 8; ++ks) {
            half8 ah[2], al[2];
            #pragma unroll
            for (int rt = 0; rt < 2; ++rt) {
                int o = swz(rt * 16 + m, ks * 32 + q * 8);
                ah[rt] = *(const half8*)&hsh[o];
                al[rt] = *(const half8*)&hsl[o];
            }
            int bbase = ks * 512 + fb;
            #pragma unroll
            for (int c = 0; c < 3; ++c) {
                if (c < ncts) {
                    half8 bh = *(const half8*)(w23h + bbase + (wv + c * 4) * 4096);
                    half8 bl = *(const half8*)(w23l + bbase + (wv + c * 4) * 4096);
                    #pragma unroll
                    for (int rt = 0; rt < 2; ++rt) {
                        a3[c][rt] = __builtin_amdgcn_mfma_f32_16x16x32_f16(ah[rt], bh, a3[c][rt], 0, 0, 0);
                        a3[c][rt] = __builtin_amdgcn_mfma_f32_16x16x32_f16(al[rt], bh, a3[c][rt], 0, 0, 0);
                        a3[c][rt] = __builtin_amdgcn_mfma_f32_16x16x32_f16(ah[rt], bl, a3[c][rt], 0, 0, 0);
                    }
                }
            }
        }
        // fp32 residual update of theta master
        #pragma unroll
        for (int c = 0; c < 3; ++c) {
            if (c < ncts) {
                int n3 = (wv + c * 4) * 16 + m;
                float b3v = (n3 < 157) ? b23g[n3] : 0.f;
                #pragma unroll
                for (int rt = 0; rt < 2; ++rt)
                    #pragma unroll
                    for (int r = 0; r < 4; ++r)
                        tm[c][rt][r] += a3[c][rt][r] + b3v;
            }
        }
        __syncthreads();   // all GEMM23 reads of h1 done

        if (it < 2) {
            // re-stage theta split-fp16 into h planes for next GEMM1
            #pragma unroll
            for (int c = 0; c < 3; ++c) {
                if (c < ncts) {
                    int n3 = (wv + c * 4) * 16 + m;
                    #pragma unroll
                    for (int rt = 0; rt < 2; ++rt)
                        #pragma unroll
                        for (int r = 0; r < 4; ++r) {
                            int row = rt * 16 + q * 4 + r;
                            u16 hi, lo; splitf(tm[c][rt][r], hi, lo);
                            hsh[row * 168 + n3] = hi;
                            hsl[row * 168 + n3] = lo;
                        }
                }
            }
        } else {
            // final: pose -> fp32 LDS (overlay x planes); betas/camera -> global fp32
            #pragma unroll
            for (int c = 0; c < 3; ++c) {
                if (c < ncts) {
                    int tile = wv + c * 4;
                    int n3 = tile * 16 + m;
                    if (tile < 9) {
                        #pragma unroll
                        for (int rt = 0; rt < 2; ++rt)
                            #pragma unroll
                            for (int r = 0; r < 4; ++r) {
                                int row = rt * 16 + q * 4 + r;
                                thf[row * 144 + n3] = tm[c][rt][r];
                            }
                    } else {  // tile 9: cols 144..159 = betas + camera
                        #pragma unroll
                        for (int rt = 0; rt < 2; ++rt)
                            #pragma unroll
                            for (int r = 0; r < 4; ++r) {
                                int row = rt * 16 + q * 4 + r;
                                long grow = rowbase + row;
                                float v = tm[c][rt][r];
                                if (m < 10)
                                    out[(size_t)NROWS * 216 + grow * 10 + m] = v;
                                else if (m < 13)
                                    out[(size_t)NROWS * 216 + (size_t)NROWS * 10 + grow * 3 + (m - 10)] = v;
                            }
                    }
                }
            }
        }
        __syncthreads();
    }

    // ============ epilogue: rot6d -> rotmat (fp32) ============
    {
        int r = t >> 3, g = t & 7;     // 8 threads per row, 3 joints each
        long grow = rowbase + r;
        #pragma unroll
        for (int jj = 0; jj < 3; ++jj) {
            int j = g * 3 + jj;
            const float* p = &thf[r * 144 + j * 6];
            float a1x = p[0], a2x = p[1], a1y = p[2], a2y = p[3], a1z = p[4], a2z = p[5];
            float n1 = fmaxf(sqrtf(a1x * a1x + a1y * a1y + a1z * a1z), 1e-12f);
            float b1x = a1x / n1, b1y = a1y / n1, b1z = a1z / n1;
            float d = b1x * a2x + b1y * a2y + b1z * a2z;
            float ux = a2x - d * b1x, uy = a2y - d * b1y, uz = a2z - d * b1z;
            float n2 = fmaxf(sqrtf(ux * ux + uy * uy + uz * uz), 1e-12f);
            float b2x = ux / n2, b2y = uy / n2, b2z = uz / n2;
            float b3x = b1y * b2z - b1z * b2y;
            float b3y = b1z * b2x - b1x * b2z;
            float b3z = b1x * b2y - b1y * b2x;
            float* o = out + (size_t)grow * 216 + j * 9;
            o[0] = b1x; o[1] = b2x; o[2] = b3x;
            o[3] = b1y; o[4] = b2y; o[5] = b3y;
            o[6] = b1z; o[7] = b2z; o[8] = b3z;
        }
    }
}

extern "C" void kernel_launch(void* const* d_in, const int* in_sizes, int n_in,
                              void* d_out, int out_size, void* d_ws, size_t ws_size,
                              hipStream_t stream) {
    const float* x  = (const float*)d_in[0];
    const float* W1 = (const float*)d_in[2];
    const float* b1 = (const float*)d_in[3];
    const float* W2 = (const float*)d_in[4];
    const float* b2 = (const float*)d_in[5];
    const float* W3 = (const float*)d_in[6];
    const float* b3 = (const float*)d_in[7];
    const float* ip = (const float*)d_in[8];
    const float* is = (const float*)d_in[9];
    const float* ic = (const float*)d_in[10];

    u16* w1h  = (u16*)d_ws;               // 16 nt * 52 kf * 128 = 106496
    u16* w1l  = w1h + 106496;
    u16* w23h = w1l + 106496;             // 10 nt * 32 kf * 128 = 40960
    u16* w23l = w23h + 40960;
    float* w23f = (float*)(w23l + 40960); // 256*157 fp32
    float* b23f = w23f + 256 * 157;       // 157 fp32

    w23_gemm<<<256, 192, 0, stream>>>(W2, W3, b2, b3, w23f, b23f);
    prep_pack<<<dim3(4, 16), 256, 0, stream>>>(W1, w1h, w1l, 413, 256, 416);
    prep_pack<<<dim3(2, 10), 256, 0, stream>>>(w23f, w23h, w23l, 256, 157, 256);

    fused_head<<<NROWS / MT, 256, 0, stream>>>(x, w1h, w1l, w23h, w23l,
                                               b1, b23f, ip, is, ic, (float*)d_out);
}

// Round 3
// 612.010 us; speedup vs baseline: 2.2603x; 1.0302x over previous
//
#include <hip/hip_runtime.h>

typedef _Float16 half8 __attribute__((ext_vector_type(8)));
typedef unsigned short ushort8 __attribute__((ext_vector_type(8)));
typedef float floatx4 __attribute__((ext_vector_type(4)));
typedef unsigned short u16;

#define NROWS 115200
#define MT 32

__device__ __forceinline__ void splitf(float f, u16& hi, u16& lo) {
    _Float16 h = (_Float16)f;
    _Float16 l = (_Float16)(f - (float)h);
    hi = __builtin_bit_cast(u16, h);
    lo = __builtin_bit_cast(u16, l);
}

// swizzled index into a [MT][256] fp16 LDS plane (16B-block XOR swizzle)
__device__ __forceinline__ int swz(int row, int col) {
    return row * 256 + ((((col >> 3)) ^ (row & 31)) << 3) + (col & 7);
}

// Pack src[K][N] fp32 into fragment-major split-fp16 planes:
// dst[((nt*kfrags + kf)*16 + m)*8 + j] = src[kf*8+j][nt*16+m]
__global__ void prep_pack(const float* __restrict__ src, u16* __restrict__ dhi,
                          u16* __restrict__ dlo, int K, int N, int Kd) {
    int kfrags = Kd >> 3;
    int nt = blockIdx.y;
    int frag = blockIdx.x * blockDim.x + threadIdx.x;
    if (frag >= kfrags * 16) return;
    int kf = frag >> 4, m = frag & 15;
    int n = nt * 16 + m;
    ushort8 vh, vl;
    #pragma unroll
    for (int j = 0; j < 8; ++j) {
        int k = kf * 8 + j;
        float v = (k < K && n < N) ? src[(size_t)k * N + n] : 0.f;
        u16 hi, lo; splitf(v, hi, lo);
        vh[j] = hi; vl[j] = lo;
    }
    size_t o = ((size_t)nt * kfrags + kf) * 128 + (size_t)m * 8;
    *(ushort8*)&dhi[o] = vh;
    *(ushort8*)&dlo[o] = vl;
}

// W23[k][n] = sum_j W2[k][j]*W3[j][n]   (256 x 157, fp32)
// b23[n]   = b3[n] + sum_j b2[j]*W3[j][n]
__global__ void w23_gemm(const float* __restrict__ W2, const float* __restrict__ W3,
                         const float* __restrict__ b2, const float* __restrict__ b3,
                         float* __restrict__ W23, float* __restrict__ b23) {
    int k = blockIdx.x, n = threadIdx.x;
    if (n >= 157) return;
    float acc = 0.f;
    for (int j = 0; j < 256; ++j)
        acc = fmaf(W2[k * 256 + j], W3[j * 157 + n], acc);
    W23[(size_t)k * 157 + n] = acc;
    if (k == 0) {
        float bb = b3[n];
        for (int j = 0; j < 256; ++j) bb = fmaf(b2[j], W3[j * 157 + n], bb);
        b23[n] = bb;
    }
}

// 512 threads = 8 waves, 64KB LDS -> 2 blocks/CU -> 4 waves/SIMD.
__global__ __launch_bounds__(512, 4) void fused_head(
    const float* __restrict__ xg,
    const u16* __restrict__ w1h, const u16* __restrict__ w1l,
    const u16* __restrict__ w23h, const u16* __restrict__ w23l,
    const float* __restrict__ b1g, const float* __restrict__ b23g,
    const float* __restrict__ ipose, const float* __restrict__ ishape, const float* __restrict__ icam,
    float* __restrict__ out)
{
    __shared__ __align__(16) u16 smem[4 * MT * 256];
    u16* xsh = smem;                  // x hi plane
    u16* xsl = smem + MT * 256;       // x lo plane
    u16* hsh = smem + 2 * MT * 256;   // h / theta hi plane
    u16* hsl = smem + 3 * MT * 256;   // h / theta lo plane
    float* thf = (float*)smem;        // [MT][144] fp32 pose (epilogue only; overlays x planes)

    const int t = threadIdx.x;
    const int lid = t & 63, wv = t >> 6;       // 8 waves
    const int q = lid >> 4, m = lid & 15;      // quad, lane-in-16
    const int fb = q * 128 + m * 8;            // fragment-local B offset
    const long rowbase = (long)blockIdx.x * MT;

    // ---- stage x tile (32 rows x 256 fp32 -> split fp16 planes) ----
    #pragma unroll
    for (int i = 0; i < 2; ++i) {
        int idx = t + i * 512;
        int r = idx >> 5, s = idx & 31;
        const float4* sp = (const float4*)(xg + (rowbase + r) * 256 + s * 8);
        float4 f0 = sp[0], f1 = sp[1];
        float fv[8] = {f0.x, f0.y, f0.z, f0.w, f1.x, f1.y, f1.z, f1.w};
        ushort8 vh, vl;
        #pragma unroll
        for (int j = 0; j < 8; ++j) {
            u16 hi, lo; splitf(fv[j], hi, lo);
            vh[j] = hi; vl[j] = lo;
        }
        int o = r * 256 + ((s ^ (r & 31)) << 3);
        *(ushort8*)&xsh[o] = vh;
        *(ushort8*)&xsl[o] = vl;
    }

    // ---- theta fp32 master in registers (GEMM23 C-frag layout) ----
    // column tile for (wv,c) = wv + c*8; valid tiles 0..9
    const int ncts = (wv < 2) ? 2 : 1;
    float tm[2][2][4];
    #pragma unroll
    for (int c = 0; c < 2; ++c) {
        int n3 = (wv + c * 8) * 16 + m;
        float v;
        if (n3 < 144)      v = ipose[n3];
        else if (n3 < 154) v = ishape[n3 - 144];
        else if (n3 < 157) v = icam[n3 - 154];
        else               v = 0.f;
        #pragma unroll
        for (int rt = 0; rt < 2; ++rt)
            #pragma unroll
            for (int r = 0; r < 4; ++r) tm[c][rt][r] = v;
    }
    #pragma unroll
    for (int c = 0; c < 2; ++c) {
        if (c < ncts) {
            int n3 = (wv + c * 8) * 16 + m;
            #pragma unroll
            for (int rt = 0; rt < 2; ++rt)
                #pragma unroll
                for (int r = 0; r < 4; ++r) {
                    int row = rt * 16 + q * 4 + r;
                    u16 hi, lo; splitf(tm[c][rt][r], hi, lo);
                    hsh[row * 168 + n3] = hi;
                    hsl[row * 168 + n3] = lo;
                }
        }
    }
    __syncthreads();

    const floatx4 zero4 = {0.f, 0.f, 0.f, 0.f};

    for (int it = 0; it < 3; ++it) {
        // ============ GEMM1: h1 = relu([x|theta] @ W1 + b1), K=416 ============
        // each wave owns 2 column tiles: nt = wv*2 + ct
        floatx4 acc[2][2];
        #pragma unroll
        for (int ct = 0; ct < 2; ++ct)
            #pragma unroll
            for (int rt = 0; rt < 2; ++rt) acc[ct][rt] = zero4;

        #pragma unroll 2
        for (int ks = 0; ks < 8; ++ks) {
            half8 ah[2], al[2];
            #pragma unroll
            for (int rt = 0; rt < 2; ++rt) {
                int o = swz(rt * 16 + m, ks * 32 + q * 8);
                ah[rt] = *(const half8*)&xsh[o];
                al[rt] = *(const half8*)&xsl[o];
            }
            int bbase = wv * 13312 + ks * 512 + fb;
            #pragma unroll
            for (int ct = 0; ct < 2; ++ct) {
                half8 bh = *(const half8*)(w1h + bbase + ct * 6656);
                half8 bl = *(const half8*)(w1l + bbase + ct * 6656);
                #pragma unroll
                for (int rt = 0; rt < 2; ++rt) {
                    acc[ct][rt] = __builtin_amdgcn_mfma_f32_16x16x32_f16(ah[rt], bh, acc[ct][rt], 0, 0, 0);
                    acc[ct][rt] = __builtin_amdgcn_mfma_f32_16x16x32_f16(al[rt], bh, acc[ct][rt], 0, 0, 0);
                    acc[ct][rt] = __builtin_amdgcn_mfma_f32_16x16x32_f16(ah[rt], bl, acc[ct][rt], 0, 0, 0);
                }
            }
        }
        #pragma unroll 1
        for (int ks = 8; ks < 13; ++ks) {
            int kp = (ks - 8) * 32 + q * 8;
            half8 ah[2], al[2];
            #pragma unroll
            for (int rt = 0; rt < 2; ++rt) {
                int o = (rt * 16 + m) * 168 + kp;
                ah[rt] = *(const half8*)&hsh[o];
                al[rt] = *(const half8*)&hsl[o];
            }
            int bbase = wv * 13312 + ks * 512 + fb;
            #pragma unroll
            for (int ct = 0; ct < 2; ++ct) {
                half8 bh = *(const half8*)(w1h + bbase + ct * 6656);
                half8 bl = *(const half8*)(w1l + bbase + ct * 6656);
                #pragma unroll
                for (int rt = 0; rt < 2; ++rt) {
                    acc[ct][rt] = __builtin_amdgcn_mfma_f32_16x16x32_f16(ah[rt], bh, acc[ct][rt], 0, 0, 0);
                    acc[ct][rt] = __builtin_amdgcn_mfma_f32_16x16x32_f16(al[rt], bh, acc[ct][rt], 0, 0, 0);
                    acc[ct][rt] = __builtin_amdgcn_mfma_f32_16x16x32_f16(ah[rt], bl, acc[ct][rt], 0, 0, 0);
                }
            }
        }
        __syncthreads();   // theta reads done -> h planes reusable
        #pragma unroll
        for (int ct = 0; ct < 2; ++ct) {
            int n = wv * 32 + ct * 16 + m;
            float bv = b1g[n];
            #pragma unroll
            for (int rt = 0; rt < 2; ++rt)
                #pragma unroll
                for (int r = 0; r < 4; ++r) {
                    int row = rt * 16 + q * 4 + r;
                    float v = fmaxf(acc[ct][rt][r] + bv, 0.f);
                    u16 hi, lo; splitf(v, hi, lo);
                    int o = swz(row, n);
                    hsh[o] = hi; hsl[o] = lo;
                }
        }
        __syncthreads();   // h1 visible

        // ======== GEMM23: theta += h1 @ (W2@W3) + b23, K=256, N=160(pad) ========
        floatx4 a3[2][2];
        #pragma unroll
        for (int c = 0; c < 2; ++c)
            #pragma unroll
            for (int rt = 0; rt < 2; ++rt) a3[c][rt] = zero4;

        #pragma unroll 2
        for (int ks = 0; ks < 8; ++ks) {
            half8 ah[2], al[2];
            #pragma unroll
            for (int rt = 0; rt < 2; ++rt) {
                int o = swz(rt * 16 + m, ks * 32 + q * 8);
                ah[rt] = *(const half8*)&hsh[o];
                al[rt] = *(const half8*)&hsl[o];
            }
            int bbase = ks * 512 + fb;
            #pragma unroll
            for (int c = 0; c < 2; ++c) {
                if (c < ncts) {
                    half8 bh = *(const half8*)(w23h + bbase + (wv + c * 8) * 4096);
                    half8 bl = *(const half8*)(w23l + bbase + (wv + c * 8) * 4096);
                    #pragma unroll
                    for (int rt = 0; rt < 2; ++rt) {
                        a3[c][rt] = __builtin_amdgcn_mfma_f32_16x16x32_f16(ah[rt], bh, a3[c][rt], 0, 0, 0);
                        a3[c][rt] = __builtin_amdgcn_mfma_f32_16x16x32_f16(al[rt], bh, a3[c][rt], 0, 0, 0);
                        a3[c][rt] = __builtin_amdgcn_mfma_f32_16x16x32_f16(ah[rt], bl, a3[c][rt], 0, 0, 0);
                    }
                }
            }
        }
        // fp32 residual update of theta master
        #pragma unroll
        for (int c = 0; c < 2; ++c) {
            if (c < ncts) {
                int n3 = (wv + c * 8) * 16 + m;
                float b3v = (n3 < 157) ? b23g[n3] : 0.f;
                #pragma unroll
                for (int rt = 0; rt < 2; ++rt)
                    #pragma unroll
                    for (int r = 0; r < 4; ++r)
                        tm[c][rt][r] += a3[c][rt][r] + b3v;
            }
        }
        __syncthreads();   // all GEMM23 reads of h1 done

        if (it < 2) {
            // re-stage theta split-fp16 into h planes for next GEMM1
            #pragma unroll
            for (int c = 0; c < 2; ++c) {
                if (c < ncts) {
                    int n3 = (wv + c * 8) * 16 + m;
                    #pragma unroll
                    for (int rt = 0; rt < 2; ++rt)
                        #pragma unroll
                        for (int r = 0; r < 4; ++r) {
                            int row = rt * 16 + q * 4 + r;
                            u16 hi, lo; splitf(tm[c][rt][r], hi, lo);
                            hsh[row * 168 + n3] = hi;
                            hsl[row * 168 + n3] = lo;
                        }
                }
            }
        } else {
            // final: pose -> fp32 LDS (overlay x planes); betas/camera -> global fp32
            #pragma unroll
            for (int c = 0; c < 2; ++c) {
                if (c < ncts) {
                    int tile = wv + c * 8;
                    int n3 = tile * 16 + m;
                    if (tile < 9) {
                        #pragma unroll
                        for (int rt = 0; rt < 2; ++rt)
                            #pragma unroll
                            for (int r = 0; r < 4; ++r) {
                                int row = rt * 16 + q * 4 + r;
                                thf[row * 144 + n3] = tm[c][rt][r];
                            }
                    } else {  // tile 9: cols 144..159 = betas + camera
                        #pragma unroll
                        for (int rt = 0; rt < 2; ++rt)
                            #pragma unroll
                            for (int r = 0; r < 4; ++r) {
                                int row = rt * 16 + q * 4 + r;
                                long grow = rowbase + row;
                                float v = tm[c][rt][r];
                                if (m < 10)
                                    out[(size_t)NROWS * 216 + grow * 10 + m] = v;
                                else if (m < 13)
                                    out[(size_t)NROWS * 216 + (size_t)NROWS * 10 + grow * 3 + (m - 10)] = v;
                            }
                    }
                }
            }
        }
        __syncthreads();
    }

    // ============ epilogue: rot6d -> rotmat (fp32) ============
    {
        int r = t >> 4, g = t & 15;    // 16 threads per row; joints g and g+16 (g<8)
        long grow = rowbase + r;
        #pragma unroll
        for (int jj = 0; jj < 2; ++jj) {
            int j = g + jj * 16;
            if (j < 24) {
                const float* p = &thf[r * 144 + j * 6];
                float a1x = p[0], a2x = p[1], a1y = p[2], a2y = p[3], a1z = p[4], a2z = p[5];
                float n1 = fmaxf(sqrtf(a1x * a1x + a1y * a1y + a1z * a1z), 1e-12f);
                float b1x = a1x / n1, b1y = a1y / n1, b1z = a1z / n1;
                float d = b1x * a2x + b1y * a2y + b1z * a2z;
                float ux = a2x - d * b1x, uy = a2y - d * b1y, uz = a2z - d * b1z;
                float n2 = fmaxf(sqrtf(ux * ux + uy * uy + uz * uz), 1e-12f);
                float b2x = ux / n2, b2y = uy / n2, b2z = uz / n2;
                float b3x = b1y * b2z - b1z * b2y;
                float b3y = b1z * b2x - b1x * b2z;
                float b3z = b1x * b2y - b1y * b2x;
                float* o = out + (size_t)grow * 216 + j * 9;
                o[0] = b1x; o[1] = b2x; o[2] = b3x;
                o[3] = b1y; o[4] = b2y; o[5] = b3y;
                o[6] = b1z; o[7] = b2z; o[8] = b3z;
            }
        }
    }
}

extern "C" void kernel_launch(void* const* d_in, const int* in_sizes, int n_in,
                              void* d_out, int out_size, void* d_ws, size_t ws_size,
                              hipStream_t stream) {
    const float* x  = (const float*)d_in[0];
    const float* W1 = (const float*)d_in[2];
    const float* b1 = (const float*)d_in[3];
    const float* W2 = (const float*)d_in[4];
    const float* b2 = (const float*)d_in[5];
    const float* W3 = (const float*)d_in[6];
    const float* b3 = (const float*)d_in[7];
    const float* ip = (const float*)d_in[8];
    const float* is = (const float*)d_in[9];
    const float* ic = (const float*)d_in[10];

    u16* w1h  = (u16*)d_ws;               // 16 nt * 52 kf * 128 = 106496
    u16* w1l  = w1h + 106496;
    u16* w23h = w1l + 106496;             // 10 nt * 32 kf * 128 = 40960
    u16* w23l = w23h + 40960;
    float* w23f = (float*)(w23l + 40960); // 256*157 fp32
    float* b23f = w23f + 256 * 157;       // 157 fp32

    w23_gemm<<<256, 192, 0, stream>>>(W2, W3, b2, b3, w23f, b23f);
    prep_pack<<<dim3(4, 16), 256, 0, stream>>>(W1, w1h, w1l, 413, 256, 416);
    prep_pack<<<dim3(2, 10), 256, 0, stream>>>(w23f, w23h, w23l, 256, 157, 256);

    fused_head<<<NROWS / MT, 512, 0, stream>>>(x, w1h, w1l, w23h, w23l,
                                               b1, b23f, ip, is, ic, (float*)d_out);
}

// Round 4
// 576.038 us; speedup vs baseline: 2.4015x; 1.0624x over previous
//
#include <hip/hip_runtime.h>

typedef _Float16 half8 __attribute__((ext_vector_type(8)));
typedef unsigned short ushort8 __attribute__((ext_vector_type(8)));
typedef float floatx4 __attribute__((ext_vector_type(4)));
typedef unsigned short u16;

#define NROWS 115200
#define MT 32

__device__ __forceinline__ void splitf(float f, u16& hi, u16& lo) {
    _Float16 h = (_Float16)f;
    _Float16 l = (_Float16)(f - (float)h);
    hi = __builtin_bit_cast(u16, h);
    lo = __builtin_bit_cast(u16, l);
}

// swizzled index into a [MT][256] fp16 LDS plane (16B-block XOR swizzle)
__device__ __forceinline__ int swz(int row, int col) {
    return row * 256 + ((((col >> 3)) ^ (row & 31)) << 3) + (col & 7);
}

// Pack src[K][N] fp32 into fragment-major split-fp16 planes:
// dst[((nt*kfrags + kf)*16 + m)*8 + j] = src[kf*8+j][nt*16+m]
__global__ void prep_pack(const float* __restrict__ src, u16* __restrict__ dhi,
                          u16* __restrict__ dlo, int K, int N, int Kd) {
    int kfrags = Kd >> 3;
    int nt = blockIdx.y;
    int frag = blockIdx.x * blockDim.x + threadIdx.x;
    if (frag >= kfrags * 16) return;
    int kf = frag >> 4, m = frag & 15;
    int n = nt * 16 + m;
    ushort8 vh, vl;
    #pragma unroll
    for (int j = 0; j < 8; ++j) {
        int k = kf * 8 + j;
        float v = (k < K && n < N) ? src[(size_t)k * N + n] : 0.f;
        u16 hi, lo; splitf(v, hi, lo);
        vh[j] = hi; vl[j] = lo;
    }
    size_t o = ((size_t)nt * kfrags + kf) * 128 + (size_t)m * 8;
    *(ushort8*)&dhi[o] = vh;
    *(ushort8*)&dlo[o] = vl;
}

// W23[k][n] = sum_j W2[k][j]*W3[j][n]   (256 x 157, fp32)
// b23[n]   = b3[n] + sum_j b2[j]*W3[j][n]
__global__ void w23_gemm(const float* __restrict__ W2, const float* __restrict__ W3,
                         const float* __restrict__ b2, const float* __restrict__ b3,
                         float* __restrict__ W23, float* __restrict__ b23) {
    int k = blockIdx.x, n = threadIdx.x;
    if (n >= 157) return;
    float acc = 0.f;
    for (int j = 0; j < 256; ++j)
        acc = fmaf(W2[k * 256 + j], W3[j * 157 + n], acc);
    W23[(size_t)k * 157 + n] = acc;
    if (k == 0) {
        float bb = b3[n];
        for (int j = 0; j < 256; ++j) bb = fmaf(b2[j], W3[j * 157 + n], bb);
        b23[n] = bb;
    }
}

// 512 threads = 8 waves, 64KB LDS -> 2 blocks/CU -> 4 waves/SIMD.
// hx = x@W1x hoisted out of the iteration loop (x is iteration-invariant);
// theta lives in the freed x planes -> 2 barriers per iteration.
__global__ __launch_bounds__(512, 4) void fused_head(
    const float* __restrict__ xg,
    const u16* __restrict__ w1h, const u16* __restrict__ w1l,
    const u16* __restrict__ w23h, const u16* __restrict__ w23l,
    const float* __restrict__ b1g, const float* __restrict__ b23g,
    const float* __restrict__ ipose, const float* __restrict__ ishape, const float* __restrict__ icam,
    float* __restrict__ out)
{
    __shared__ __align__(16) u16 smem[4 * MT * 256];
    u16* P0  = smem;                  // x hi plane (swz) -> theta hi (stride 168)
    u16* P1  = smem + 8192;           // x lo plane (swz) -> theta lo (stride 168)
    u16* hsh = smem + 16384;          // h1 hi plane (swz)
    u16* hsl = smem + 24576;          // h1 lo plane (swz)
    float* thf = (float*)(smem + 16384); // [MT][144] fp32 pose (final; overlays h planes)

    const int t = threadIdx.x;
    const int lid = t & 63, wv = t >> 6;       // 8 waves
    const int q = lid >> 4, m = lid & 15;      // quad, lane-in-16
    const int fb = q * 128 + m * 8;            // fragment-local B offset
    const long rowbase = (long)blockIdx.x * MT;

    // ---- stage x tile (32 rows x 256 fp32 -> split fp16 planes) ----
    #pragma unroll
    for (int i = 0; i < 2; ++i) {
        int idx = t + i * 512;
        int r = idx >> 5, s = idx & 31;
        const float4* sp = (const float4*)(xg + (rowbase + r) * 256 + s * 8);
        float4 f0 = sp[0], f1 = sp[1];
        float fv[8] = {f0.x, f0.y, f0.z, f0.w, f1.x, f1.y, f1.z, f1.w};
        ushort8 vh, vl;
        #pragma unroll
        for (int j = 0; j < 8; ++j) {
            u16 hi, lo; splitf(fv[j], hi, lo);
            vh[j] = hi; vl[j] = lo;
        }
        int o = r * 256 + ((s ^ (r & 31)) << 3);
        *(ushort8*)&P0[o] = vh;
        *(ushort8*)&P1[o] = vl;
    }

    // ---- theta fp32 master in registers (GEMM23 C-frag layout) ----
    // column tile for (wv,c) = wv + c*8; valid tiles 0..9
    const int ncts = (wv < 2) ? 2 : 1;
    float tm[2][2][4];
    #pragma unroll
    for (int c = 0; c < 2; ++c) {
        int n3 = (wv + c * 8) * 16 + m;
        float v;
        if (n3 < 144)      v = ipose[n3];
        else if (n3 < 154) v = ishape[n3 - 144];
        else if (n3 < 157) v = icam[n3 - 154];
        else               v = 0.f;
        #pragma unroll
        for (int rt = 0; rt < 2; ++rt)
            #pragma unroll
            for (int r = 0; r < 4; ++r) tm[c][rt][r] = v;
    }
    __syncthreads();   // x planes staged

    const floatx4 zero4 = {0.f, 0.f, 0.f, 0.f};

    // ============ hoisted: hx = x @ W1x  (K=256, once) ============
    floatx4 hx[2][2];
    #pragma unroll
    for (int ct = 0; ct < 2; ++ct)
        #pragma unroll
        for (int rt = 0; rt < 2; ++rt) hx[ct][rt] = zero4;

    #pragma unroll 2
    for (int ks = 0; ks < 8; ++ks) {
        half8 ah[2], al[2];
        #pragma unroll
        for (int rt = 0; rt < 2; ++rt) {
            int o = swz(rt * 16 + m, ks * 32 + q * 8);
            ah[rt] = *(const half8*)&P0[o];
            al[rt] = *(const half8*)&P1[o];
        }
        int bbase = wv * 13312 + ks * 512 + fb;
        #pragma unroll
        for (int ct = 0; ct < 2; ++ct) {
            half8 bh = *(const half8*)(w1h + bbase + ct * 6656);
            half8 bl = *(const half8*)(w1l + bbase + ct * 6656);
            #pragma unroll
            for (int rt = 0; rt < 2; ++rt) {
                hx[ct][rt] = __builtin_amdgcn_mfma_f32_16x16x32_f16(ah[rt], bh, hx[ct][rt], 0, 0, 0);
                hx[ct][rt] = __builtin_amdgcn_mfma_f32_16x16x32_f16(al[rt], bh, hx[ct][rt], 0, 0, 0);
                hx[ct][rt] = __builtin_amdgcn_mfma_f32_16x16x32_f16(ah[rt], bl, hx[ct][rt], 0, 0, 0);
            }
        }
    }
    __syncthreads();   // all x-plane reads done -> P0/P1 free for theta

    // ---- theta0 -> P0/P1 (stride 168) ----
    #pragma unroll
    for (int c = 0; c < 2; ++c) {
        if (c < ncts) {
            int n3 = (wv + c * 8) * 16 + m;
            #pragma unroll
            for (int rt = 0; rt < 2; ++rt)
                #pragma unroll
                for (int r = 0; r < 4; ++r) {
                    int row = rt * 16 + q * 4 + r;
                    u16 hi, lo; splitf(tm[c][rt][r], hi, lo);
                    P0[row * 168 + n3] = hi;
                    P1[row * 168 + n3] = lo;
                }
        }
    }
    __syncthreads();

    for (int it = 0; it < 3; ++it) {
        // ===== GEMM1 theta-part: acc = hx + theta @ W1t, K=160 =====
        floatx4 acc[2][2];
        #pragma unroll
        for (int ct = 0; ct < 2; ++ct)
            #pragma unroll
            for (int rt = 0; rt < 2; ++rt) acc[ct][rt] = hx[ct][rt];

        #pragma unroll 1
        for (int ks = 8; ks < 13; ++ks) {
            int kp = (ks - 8) * 32 + q * 8;
            half8 ah[2], al[2];
            #pragma unroll
            for (int rt = 0; rt < 2; ++rt) {
                int o = (rt * 16 + m) * 168 + kp;
                ah[rt] = *(const half8*)&P0[o];
                al[rt] = *(const half8*)&P1[o];
            }
            int bbase = wv * 13312 + ks * 512 + fb;
            #pragma unroll
            for (int ct = 0; ct < 2; ++ct) {
                half8 bh = *(const half8*)(w1h + bbase + ct * 6656);
                half8 bl = *(const half8*)(w1l + bbase + ct * 6656);
                #pragma unroll
                for (int rt = 0; rt < 2; ++rt) {
                    acc[ct][rt] = __builtin_amdgcn_mfma_f32_16x16x32_f16(ah[rt], bh, acc[ct][rt], 0, 0, 0);
                    acc[ct][rt] = __builtin_amdgcn_mfma_f32_16x16x32_f16(al[rt], bh, acc[ct][rt], 0, 0, 0);
                    acc[ct][rt] = __builtin_amdgcn_mfma_f32_16x16x32_f16(ah[rt], bl, acc[ct][rt], 0, 0, 0);
                }
            }
        }
        // epi: bias + relu -> h planes (prev readers finished before last syncB)
        #pragma unroll
        for (int ct = 0; ct < 2; ++ct) {
            int n = wv * 32 + ct * 16 + m;
            float bv = b1g[n];
            #pragma unroll
            for (int rt = 0; rt < 2; ++rt)
                #pragma unroll
                for (int r = 0; r < 4; ++r) {
                    int row = rt * 16 + q * 4 + r;
                    float v = fmaxf(acc[ct][rt][r] + bv, 0.f);
                    u16 hi, lo; splitf(v, hi, lo);
                    int o = swz(row, n);
                    hsh[o] = hi; hsl[o] = lo;
                }
        }
        __syncthreads();   // A: h1 visible (theta reads also all done)

        // ======== GEMM23: theta += h1 @ (W2@W3) + b23, K=256, N=160(pad) ========
        floatx4 a3[2][2];
        #pragma unroll
        for (int c = 0; c < 2; ++c)
            #pragma unroll
            for (int rt = 0; rt < 2; ++rt) a3[c][rt] = zero4;

        #pragma unroll 2
        for (int ks = 0; ks < 8; ++ks) {
            half8 ah[2], al[2];
            #pragma unroll
            for (int rt = 0; rt < 2; ++rt) {
                int o = swz(rt * 16 + m, ks * 32 + q * 8);
                ah[rt] = *(const half8*)&hsh[o];
                al[rt] = *(const half8*)&hsl[o];
            }
            int bbase = ks * 512 + fb;
            #pragma unroll
            for (int c = 0; c < 2; ++c) {
                if (c < ncts) {
                    half8 bh = *(const half8*)(w23h + bbase + (wv + c * 8) * 4096);
                    half8 bl = *(const half8*)(w23l + bbase + (wv + c * 8) * 4096);
                    #pragma unroll
                    for (int rt = 0; rt < 2; ++rt) {
                        a3[c][rt] = __builtin_amdgcn_mfma_f32_16x16x32_f16(ah[rt], bh, a3[c][rt], 0, 0, 0);
                        a3[c][rt] = __builtin_amdgcn_mfma_f32_16x16x32_f16(al[rt], bh, a3[c][rt], 0, 0, 0);
                        a3[c][rt] = __builtin_amdgcn_mfma_f32_16x16x32_f16(ah[rt], bl, a3[c][rt], 0, 0, 0);
                    }
                }
            }
        }
        // fp32 residual update of theta master
        #pragma unroll
        for (int c = 0; c < 2; ++c) {
            if (c < ncts) {
                int n3 = (wv + c * 8) * 16 + m;
                float b3v = (n3 < 157) ? b23g[n3] : 0.f;
                #pragma unroll
                for (int rt = 0; rt < 2; ++rt)
                    #pragma unroll
                    for (int r = 0; r < 4; ++r)
                        tm[c][rt][r] += a3[c][rt][r] + b3v;
            }
        }

        if (it < 2) {
            // restage theta into P0/P1 (disjoint from h planes; GEMM1-theta
            // readers of this iter all finished before sync A)
            #pragma unroll
            for (int c = 0; c < 2; ++c) {
                if (c < ncts) {
                    int n3 = (wv + c * 8) * 16 + m;
                    #pragma unroll
                    for (int rt = 0; rt < 2; ++rt)
                        #pragma unroll
                        for (int r = 0; r < 4; ++r) {
                            int row = rt * 16 + q * 4 + r;
                            u16 hi, lo; splitf(tm[c][rt][r], hi, lo);
                            P0[row * 168 + n3] = hi;
                            P1[row * 168 + n3] = lo;
                        }
                }
            }
            __syncthreads();   // B: theta' visible; all GEMM23 h reads done
        } else {
            __syncthreads();   // B: all GEMM23 h-plane reads done -> thf may overlay
            // final: pose -> fp32 LDS (overlays h planes); betas/camera -> global
            #pragma unroll
            for (int c = 0; c < 2; ++c) {
                if (c < ncts) {
                    int tile = wv + c * 8;
                    int n3 = tile * 16 + m;
                    if (tile < 9) {
                        #pragma unroll
                        for (int rt = 0; rt < 2; ++rt)
                            #pragma unroll
                            for (int r = 0; r < 4; ++r) {
                                int row = rt * 16 + q * 4 + r;
                                thf[row * 144 + n3] = tm[c][rt][r];
                            }
                    } else {  // tile 9: cols 144..159 = betas + camera
                        #pragma unroll
                        for (int rt = 0; rt < 2; ++rt)
                            #pragma unroll
                            for (int r = 0; r < 4; ++r) {
                                int row = rt * 16 + q * 4 + r;
                                long grow = rowbase + row;
                                float v = tm[c][rt][r];
                                if (m < 10)
                                    out[(size_t)NROWS * 216 + grow * 10 + m] = v;
                                else if (m < 13)
                                    out[(size_t)NROWS * 216 + (size_t)NROWS * 10 + grow * 3 + (m - 10)] = v;
                            }
                    }
                }
            }
            __syncthreads();   // thf visible
        }
    }

    // ============ epilogue: rot6d -> rotmat (fp32), 8 threads/row ============
    if (t < 256) {
        int r = t >> 3, g = t & 7;     // 8 threads per row, 3 consecutive joints each
        long grow = rowbase + r;
        #pragma unroll
        for (int jj = 0; jj < 3; ++jj) {
            int j = g * 3 + jj;
            const float* p = &thf[r * 144 + j * 6];
            float a1x = p[0], a2x = p[1], a1y = p[2], a2y = p[3], a1z = p[4], a2z = p[5];
            float n1 = fmaxf(sqrtf(a1x * a1x + a1y * a1y + a1z * a1z), 1e-12f);
            float b1x = a1x / n1, b1y = a1y / n1, b1z = a1z / n1;
            float d = b1x * a2x + b1y * a2y + b1z * a2z;
            float ux = a2x - d * b1x, uy = a2y - d * b1y, uz = a2z - d * b1z;
            float n2 = fmaxf(sqrtf(ux * ux + uy * uy + uz * uz), 1e-12f);
            float b2x = ux / n2, b2y = uy / n2, b2z = uz / n2;
            float b3x = b1y * b2z - b1z * b2y;
            float b3y = b1z * b2x - b1x * b2z;
            float b3z = b1x * b2y - b1y * b2x;
            float* o = out + (size_t)grow * 216 + j * 9;
            o[0] = b1x; o[1] = b2x; o[2] = b3x;
            o[3] = b1y; o[4] = b2y; o[5] = b3y;
            o[6] = b1z; o[7] = b2z; o[8] = b3z;
        }
    }
}

extern "C" void kernel_launch(void* const* d_in, const int* in_sizes, int n_in,
                              void* d_out, int out_size, void* d_ws, size_t ws_size,
                              hipStream_t stream) {
    const float* x  = (const float*)d_in[0];
    const float* W1 = (const float*)d_in[2];
    const float* b1 = (const float*)d_in[3];
    const float* W2 = (const float*)d_in[4];
    const float* b2 = (const float*)d_in[5];
    const float* W3 = (const float*)d_in[6];
    const float* b3 = (const float*)d_in[7];
    const float* ip = (const float*)d_in[8];
    const float* is = (const float*)d_in[9];
    const float* ic = (const float*)d_in[10];

    u16* w1h  = (u16*)d_ws;               // 16 nt * 52 kf * 128 = 106496
    u16* w1l  = w1h + 106496;
    u16* w23h = w1l + 106496;             // 10 nt * 32 kf * 128 = 40960
    u16* w23l = w23h + 40960;
    float* w23f = (float*)(w23l + 40960); // 256*157 fp32
    float* b23f = w23f + 256 * 157;       // 157 fp32

    w23_gemm<<<256, 192, 0, stream>>>(W2, W3, b2, b3, w23f, b23f);
    prep_pack<<<dim3(4, 16), 256, 0, stream>>>(W1, w1h, w1l, 413, 256, 416);
    prep_pack<<<dim3(2, 10), 256, 0, stream>>>(w23f, w23h, w23l, 256, 157, 256);

    fused_head<<<NROWS / MT, 512, 0, stream>>>(x, w1h, w1l, w23h, w23l,
                                               b1, b23f, ip, is, ic, (float*)d_out);
}